// Round 7
// baseline (195.375 us; speedup 1.0000x reference)
//
#include <hip/hip_runtime.h>

#define BB   4
#define NN   16384
#define KK   32
#define HID  128
#define OUTF 64

typedef _Float16 f16x8 __attribute__((ext_vector_type(8)));
typedef _Float16 f16x4 __attribute__((ext_vector_type(4)));
typedef _Float16 f16x2 __attribute__((ext_vector_type(2)));
typedef float    f32x4 __attribute__((ext_vector_type(4)));

static __device__ __forceinline__ unsigned short h2u(_Float16 h) {
    union { _Float16 h; unsigned short u; } c; c.h = h; return c.u;
}
static __device__ __forceinline__ _Float16 u2h(unsigned short u) {
    union { _Float16 h; unsigned short u; } c; c.u = u; return c.h;
}

// ---------------------------------------------------------------------------
// prep_all: ONE kernel, no inter-block deps. (verified R6)
// blocks 0..23   : gB1 tile pack (24 tiles, 16x16x32 B-layout)
// blocks 24..39  : gW2 tile pack (16 tiles) — NOW pre-scaled by 1/32 (mean fold)
// blocks 40..2343: feat fp32->fp16 + points->float4
// block  2344    : b1c = mlp_b1 + pe_b2 @ W1b
// ---------------------------------------------------------------------------
__global__ __launch_bounds__(256) void prep_all(
    const float* __restrict__ pe_w2, const float* __restrict__ pe_b2,
    const float* __restrict__ mlp_w1, const float* __restrict__ mlp_b1,
    const float* __restrict__ mlp_w2,
    const float* __restrict__ features, const float* __restrict__ points,
    _Float16* __restrict__ gB1, _Float16* __restrict__ gW2,
    float* __restrict__ b1c,
    _Float16* __restrict__ feat16, float4* __restrict__ pts4)
{
    const int bid = blockIdx.x, tid = threadIdx.x;
    if (bid >= 40) {
        if (bid == 2344) {
            if (tid < HID) {
                float a = mlp_b1[tid];
#pragma unroll 16
                for (int c = 0; c < 64; ++c)
                    a = fmaf(pe_b2[c], mlp_w1[(32 + c) * HID + tid], a);
                b1c[tid] = a;
            }
            return;
        }
        int t = (bid - 40) * 256 + tid;
        if (t < BB * NN * 8) {
            float4 v = ((const float4*)features)[t];
            f16x4 h;
            h[0] = (_Float16)v.x; h[1] = (_Float16)v.y;
            h[2] = (_Float16)v.z; h[3] = (_Float16)v.w;
            *(f16x4*)(feat16 + (size_t)t * 4) = h;
        } else {
            int i = t - BB * NN * 8;
            if (i < BB * NN) {
                const float* p = points + (size_t)i * 3;
                pts4[i] = make_float4(p[0], p[1], p[2], 0.f);
            }
        }
        return;
    }
    if (bid < 24) {   // gB1: tile (ks,nt); element e: l=e>>3, j=e&7
        int ks = bid >> 3, nt = bid & 7;
        for (int e = tid; e < 512; e += 256) {
            int l = e >> 3, j = e & 7;
            int k = ks * 32 + (l >> 4) * 8 + j;
            int n = nt * 16 + (l & 15);
            float v;
            if (k < 32) {
                v = mlp_w1[k * HID + n];
            } else {
                int r = k - 32;
                v = 0.f;
#pragma unroll 16
                for (int c = 0; c < 64; ++c)
                    v = fmaf(pe_w2[r * 64 + c], mlp_w1[(32 + c) * HID + n], v);
            }
            gB1[bid * 512 + e] = (_Float16)v;
        }
    } else {          // gW2 — pre-scaled by 1/32 so hm stores skip the mean mul
        int tb = bid - 24;
        int ks = tb >> 2, nt = tb & 3;
        for (int e = tid; e < 512; e += 256) {
            int l = e >> 3, j = e & 7;
            int k = ks * 32 + (l >> 4) * 8 + j;
            int n = nt * 16 + (l & 15);
            gW2[tb * 512 + e] = (_Float16)(mlp_w2[k * OUTF + n] * 0.03125f);
        }
    }
}

// ---------------------------------------------------------------------------
// Main: 1024 blocks x 4 waves; one wave = 16 points, pairs per iteration.
// KEY CHANGE vs R6: sHM halved to 8-point groups (epilogue runs twice) ->
// LDS 35.8 KB -> 4 blocks/CU (16 waves/CU) for better latency hiding.
// launch_bounds(256,4): VGPR cap 128, kernel needs ~70 -> no spill.
// ---------------------------------------------------------------------------
__global__ __launch_bounds__(256, 4) void DensityAwareFeatureAggregator_main(
    const float4* __restrict__ pts4,      // (B*N) padded, global index
    const _Float16* __restrict__ feat16,  // (B*N,32) f16
    const int*   __restrict__ nbr,        // (B,N,32)
    const float* __restrict__ pe_w1,      // (3,64)
    const float* __restrict__ pe_b1,      // (64)
    const float* __restrict__ b1c,        // (128) fused bias
    const _Float16* __restrict__ gB1,     // W1c frags (24 tiles)
    const _Float16* __restrict__ gW2,     // W2 frags (16 tiles, pre-scaled /32)
    const float* __restrict__ b2g,        // (64)
    float* __restrict__ out)              // (B,N,64)
{
    __shared__ __align__(16) _Float16 sB1[24 * 512];    // 24576 B
    __shared__ __align__(16) f16x8    sTabH[32];        //   512 B
    __shared__ __align__(16) ushort4  sRI[4][64];       //  2048 B
    __shared__ __align__(16) _Float16 sHM[4][8 * 136];  //  8704 B  (8-pt groups)
    // total 35840 B -> 4 blocks/CU, 16 waves/CU

    const int t = threadIdx.x;
    {
        const uint4* g = (const uint4*)gB1;
        uint4* d = (uint4*)sB1;
        for (int i = t; i < 1536; i += 256) d[i] = g[i];
    }
    if (t < 32) {   // col-pair tables: {x0,x1,y0,y1,z0,z1,b0,b1}
        int cp = t;
        f16x8 e;
        e[0] = (_Float16)pe_w1[2 * cp];       e[1] = (_Float16)pe_w1[2 * cp + 1];
        e[2] = (_Float16)pe_w1[64 + 2 * cp];  e[3] = (_Float16)pe_w1[64 + 2 * cp + 1];
        e[4] = (_Float16)pe_w1[128 + 2 * cp]; e[5] = (_Float16)pe_w1[128 + 2 * cp + 1];
        e[6] = (_Float16)pe_b1[2 * cp];       e[7] = (_Float16)pe_b1[2 * cp + 1];
        sTabH[cp] = e;
    }
    __syncthreads();

    const int w = t >> 6, l = t & 63, q = l >> 4, c16 = l & 15;
    const int nb   = (blockIdx.x & 7) * 128 + (blockIdx.x >> 3);
    const int base = (nb * 4 + w) * 16;
    const int bo   = base & ~(NN - 1);   // batch offset into flat point ids

    f16x8 tab1[4], tab2[4];
#pragma unroll
    for (int u = 0; u < 4; ++u) {
        tab1[u] = sTabH[q * 4 + u];
        tab2[u] = sTabH[16 + q * 4 + u];
    }
    float bias1[8];
#pragma unroll
    for (int nt = 0; nt < 8; ++nt) bias1[nt] = b1c[nt * 16 + c16];
    float bias2[4];
#pragma unroll
    for (int nt = 0; nt < 4; ++nt) bias2[nt] = b2g[nt * 16 + c16];

    const f16x8* B1f = (const f16x8*)sB1;
    const f16x8* W2f = (const f16x8*)gW2;
    _Float16* hmw = &sHM[w][0];

#pragma unroll 1
    for (int g = 0; g < 2; ++g) {          // two 8-point groups
#pragma unroll 1
        for (int p2 = 0; p2 < 4; ++p2) {   // 4 pairs per group
            const int mA = base + g * 8 + 2 * p2;
            // ---- full-wave staging: lanes 0-31 point A, 32-63 point B ----
            int idx = nbr[(size_t)mA * KK + l];
            float4 pc = pts4[mA + (l >> 5)];
            float4 pn = pts4[bo + idx];
            ushort4 st;
            st.x = h2u((_Float16)(pn.x - pc.x));
            st.y = h2u((_Float16)(pn.y - pc.y));
            st.z = h2u((_Float16)(pn.z - pc.z));
            st.w = (unsigned short)idx;
            sRI[w][l] = st;
            ushort4 eA0 = sRI[w][c16];
            ushort4 eA1 = sRI[w][16 + c16];
            ushort4 eB0 = sRI[w][32 + c16];
            ushort4 eB1 = sRI[w][48 + c16];

            // ---- feature A-frags from fp16 global (MFMA A layout) ----
            f16x8 afA0 = ((const f16x8*)(feat16 + ((size_t)(bo + eA0.w)) * 32))[q];
            f16x8 afA1 = ((const f16x8*)(feat16 + ((size_t)(bo + eA1.w)) * 32))[q];
            f16x8 afB0 = ((const f16x8*)(feat16 + ((size_t)(bo + eB0.w)) * 32))[q];
            f16x8 afB1 = ((const f16x8*)(feat16 + ((size_t)(bo + eB1.w)) * 32))[q];

            // ---- pe A-frags, packed f16x2 math ----
            f16x8 apA10, apA20, apA11, apA21, apB10, apB20, apB11, apB21;
            {
                const ushort4 ev[4] = { eA0, eA1, eB0, eB1 };
                f16x8* o1[4] = { &apA10, &apA11, &apB10, &apB11 };
                f16x8* o2[4] = { &apA20, &apA21, &apB20, &apB21 };
#pragma unroll
                for (int s = 0; s < 4; ++s) {
                    _Float16 hx = u2h(ev[s].x), hy = u2h(ev[s].y), hz = u2h(ev[s].z);
                    f16x2 rx = { hx, hx }, ry = { hy, hy }, rz = { hz, hz };
                    f16x8 r1, r2;
#pragma unroll
                    for (int u = 0; u < 4; ++u) {
                        f16x8 tA = tab1[u], tB = tab2[u];
                        f16x2 v1 = (f16x2){ tA[6], tA[7] };
                        v1 += (f16x2){ tA[0], tA[1] } * rx;
                        v1 += (f16x2){ tA[2], tA[3] } * ry;
                        v1 += (f16x2){ tA[4], tA[5] } * rz;
                        f16x2 v2 = (f16x2){ tB[6], tB[7] };
                        v2 += (f16x2){ tB[0], tB[1] } * rx;
                        v2 += (f16x2){ tB[2], tB[3] } * ry;
                        v2 += (f16x2){ tB[4], tB[5] } * rz;
                        _Float16 z = (_Float16)0.f;
                        r1[2*u]   = v1[0] > z ? v1[0] : z;
                        r1[2*u+1] = v1[1] > z ? v1[1] : z;
                        r2[2*u]   = v2[0] > z ? v2[0] : z;
                        r2[2*u+1] = v2[1] > z ? v2[1] : z;
                    }
                    *o1[s] = r1; *o2[s] = r2;
                }
            }

            // ---- per-N-tile: 3 shared B-frags, 12 MFMAs, reduce ----
#pragma unroll 2
            for (int nt = 0; nt < 8; ++nt) {
                f16x8 bf0 = B1f[nt * 64 + l];
                f16x8 bf1 = B1f[(8 + nt) * 64 + l];
                f16x8 bf2 = B1f[(16 + nt) * 64 + l];
                f32x4 aA0, aA1, aB0, aB1;
                aA0[0] = aA0[1] = aA0[2] = aA0[3] = bias1[nt];
                aA1 = aA0; aB0 = aA0; aB1 = aA0;
                aA0 = __builtin_amdgcn_mfma_f32_16x16x32_f16(afA0,  bf0, aA0, 0, 0, 0);
                aA1 = __builtin_amdgcn_mfma_f32_16x16x32_f16(afA1,  bf0, aA1, 0, 0, 0);
                aB0 = __builtin_amdgcn_mfma_f32_16x16x32_f16(afB0,  bf0, aB0, 0, 0, 0);
                aB1 = __builtin_amdgcn_mfma_f32_16x16x32_f16(afB1,  bf0, aB1, 0, 0, 0);
                aA0 = __builtin_amdgcn_mfma_f32_16x16x32_f16(apA10, bf1, aA0, 0, 0, 0);
                aA1 = __builtin_amdgcn_mfma_f32_16x16x32_f16(apA11, bf1, aA1, 0, 0, 0);
                aB0 = __builtin_amdgcn_mfma_f32_16x16x32_f16(apB10, bf1, aB0, 0, 0, 0);
                aB1 = __builtin_amdgcn_mfma_f32_16x16x32_f16(apB11, bf1, aB1, 0, 0, 0);
                aA0 = __builtin_amdgcn_mfma_f32_16x16x32_f16(apA20, bf2, aA0, 0, 0, 0);
                aA1 = __builtin_amdgcn_mfma_f32_16x16x32_f16(apA21, bf2, aA1, 0, 0, 0);
                aB0 = __builtin_amdgcn_mfma_f32_16x16x32_f16(apB20, bf2, aB0, 0, 0, 0);
                aB1 = __builtin_amdgcn_mfma_f32_16x16x32_f16(apB21, bf2, aB1, 0, 0, 0);

                float sA = fmaxf(aA0[0], 0.f) + fmaxf(aA0[1], 0.f)
                         + fmaxf(aA0[2], 0.f) + fmaxf(aA0[3], 0.f)
                         + fmaxf(aA1[0], 0.f) + fmaxf(aA1[1], 0.f)
                         + fmaxf(aA1[2], 0.f) + fmaxf(aA1[3], 0.f);
                float sB = fmaxf(aB0[0], 0.f) + fmaxf(aB0[1], 0.f)
                         + fmaxf(aB0[2], 0.f) + fmaxf(aB0[3], 0.f)
                         + fmaxf(aB1[0], 0.f) + fmaxf(aB1[1], 0.f)
                         + fmaxf(aB1[2], 0.f) + fmaxf(aB1[3], 0.f);
                sA += __shfl_xor(sA, 16, 64);
                sA += __shfl_xor(sA, 32, 64);
                sB += __shfl_xor(sB, 16, 64);
                sB += __shfl_xor(sB, 32, 64);
                if (q == 0) {
                    hmw[(2 * p2) * 136 + nt * 16 + c16]     = (_Float16)sA;
                    hmw[(2 * p2 + 1) * 136 + nt * 16 + c16] = (_Float16)sB;
                }
            }
        }

        // ---- epilogue for this 8-point group: OUT(8x64) = HM @ W2s + b2 ----
        // A rows c16>=8 alias rows 0-7 (c16&7): in-bounds reads; their D rows
        // are simply not stored (row r of D depends only on row r of A).
        f32x4 acc2[4];
#pragma unroll
        for (int nt = 0; nt < 4; ++nt) {
            f32x4 z; z[0] = z[1] = z[2] = z[3] = bias2[nt];
            acc2[nt] = z;
        }
#pragma unroll
        for (int ks = 0; ks < 4; ++ks) {
            f16x8 a2 = *(const f16x8*)&hmw[(c16 & 7) * 136 + ks * 32 + q * 8];
#pragma unroll
            for (int nt = 0; nt < 4; ++nt) {
                f16x8 bf = W2f[(ks * 4 + nt) * 64 + l];
                acc2[nt] = __builtin_amdgcn_mfma_f32_16x16x32_f16(a2, bf, acc2[nt], 0, 0, 0);
            }
        }
        if (q < 2) {
#pragma unroll
            for (int nt = 0; nt < 4; ++nt)
#pragma unroll
                for (int r = 0; r < 4; ++r)
                    out[(size_t)(base + g * 8 + q * 4 + r) * OUTF + nt * 16 + c16]
                        = acc2[nt][r];
        }
    }
}

// ---------------------------------------------------------------------------
extern "C" void kernel_launch(void* const* d_in, const int* in_sizes, int n_in,
                              void* d_out, int out_size, void* d_ws, size_t ws_size,
                              hipStream_t stream)
{
    const float* points   = (const float*)d_in[0];
    const float* features = (const float*)d_in[1];
    // d_in[2] density: provably unused (softmax over K identical values = 1/K)
    const int*   nbr      = (const int*)d_in[3];
    const float* pe_w1    = (const float*)d_in[4];
    const float* pe_b1    = (const float*)d_in[5];
    const float* pe_w2    = (const float*)d_in[6];
    const float* pe_b2    = (const float*)d_in[7];
    const float* mlp_w1   = (const float*)d_in[8];
    const float* mlp_b1   = (const float*)d_in[9];
    const float* mlp_w2   = (const float*)d_in[10];
    const float* mlp_b2   = (const float*)d_in[11];

    float* wsf = (float*)d_ws;
    float*    b1c    = wsf;                         // 128 f32
    _Float16* gB1    = (_Float16*)(wsf + 128);      // 12288 f16
    _Float16* gW2    = (_Float16*)(wsf + 6272);     // 8192 f16
    float4*   pts4   = (float4*)(wsf + 10368);      // 65536 float4
    _Float16* feat16 = (_Float16*)(wsf + 272512);   // 2097152 f16

    prep_all<<<2345, 256, 0, stream>>>(
        pe_w2, pe_b2, mlp_w1, mlp_b1, mlp_w2, features, points,
        gB1, gW2, b1c, feat16, pts4);

    DensityAwareFeatureAggregator_main<<<1024, 256, 0, stream>>>(
        pts4, feat16, nbr, pe_w1, pe_b1, b1c, gB1, gW2, mlp_b2,
        (float*)d_out);
}

// Round 8
// 178.367 us; speedup vs baseline: 1.0954x; 1.0954x over previous
//
#include <hip/hip_runtime.h>

#define BB   4
#define NN   16384
#define KK   32
#define HID  128
#define OUTF 64

typedef _Float16 f16x8 __attribute__((ext_vector_type(8)));
typedef _Float16 f16x4 __attribute__((ext_vector_type(4)));
typedef _Float16 f16x2 __attribute__((ext_vector_type(2)));
typedef float    f32x4 __attribute__((ext_vector_type(4)));

static __device__ __forceinline__ unsigned short h2u(_Float16 h) {
    union { _Float16 h; unsigned short u; } c; c.h = h; return c.u;
}
static __device__ __forceinline__ _Float16 u2h(unsigned short u) {
    union { _Float16 h; unsigned short u; } c; c.u = u; return c.h;
}

// pe column-pair MAC: v = bias2 + t.xy*rx + t.zw*ry + t[4:5]*rz  (v_pk_fma_f16)
#define PE_HALF(T, RX, RY, RZ)                                              \
    (__builtin_shufflevector((T), (T), 6, 7)                                \
     + __builtin_shufflevector((T), (T), 0, 1) * (RX)                       \
     + __builtin_shufflevector((T), (T), 2, 3) * (RY)                       \
     + __builtin_shufflevector((T), (T), 4, 5) * (RZ))

// Array-free pe fragment builder: named temporaries only, relu via pk_max,
// f16x8 assembly via shufflevector (register placement, no insert chains).
#define PE_FRAGS(E, O1, O2)                                                 \
    do {                                                                    \
        _Float16 _hx = u2h((E).x), _hy = u2h((E).y), _hz = u2h((E).z);      \
        f16x2 _rx = { _hx, _hx }, _ry = { _hy, _hy }, _rz = { _hz, _hz };   \
        f16x2 _z = { (_Float16)0.f, (_Float16)0.f };                        \
        f16x2 _a0 = __builtin_elementwise_max(PE_HALF(tab1[0], _rx, _ry, _rz), _z); \
        f16x2 _a1 = __builtin_elementwise_max(PE_HALF(tab1[1], _rx, _ry, _rz), _z); \
        f16x2 _a2 = __builtin_elementwise_max(PE_HALF(tab1[2], _rx, _ry, _rz), _z); \
        f16x2 _a3 = __builtin_elementwise_max(PE_HALF(tab1[3], _rx, _ry, _rz), _z); \
        f16x2 _b0 = __builtin_elementwise_max(PE_HALF(tab2[0], _rx, _ry, _rz), _z); \
        f16x2 _b1 = __builtin_elementwise_max(PE_HALF(tab2[1], _rx, _ry, _rz), _z); \
        f16x2 _b2 = __builtin_elementwise_max(PE_HALF(tab2[2], _rx, _ry, _rz), _z); \
        f16x2 _b3 = __builtin_elementwise_max(PE_HALF(tab2[3], _rx, _ry, _rz), _z); \
        f16x4 _al = __builtin_shufflevector(_a0, _a1, 0, 1, 2, 3);          \
        f16x4 _ah = __builtin_shufflevector(_a2, _a3, 0, 1, 2, 3);          \
        f16x4 _bl = __builtin_shufflevector(_b0, _b1, 0, 1, 2, 3);          \
        f16x4 _bh = __builtin_shufflevector(_b2, _b3, 0, 1, 2, 3);          \
        O1 = __builtin_shufflevector(_al, _ah, 0, 1, 2, 3, 4, 5, 6, 7);     \
        O2 = __builtin_shufflevector(_bl, _bh, 0, 1, 2, 3, 4, 5, 6, 7);     \
    } while (0)

// ---------------------------------------------------------------------------
// prep_all: ONE kernel, no inter-block deps. (verified R6/R7)
// blocks 0..23   : gB1 tile pack (24 tiles, 16x16x32 B-layout)
// blocks 24..39  : gW2 tile pack (16 tiles), pre-scaled by 1/32 (mean fold)
// blocks 40..2343: feat fp32->fp16 + points->float4
// block  2344    : b1c = mlp_b1 + pe_b2 @ W1b
// ---------------------------------------------------------------------------
__global__ __launch_bounds__(256) void prep_all(
    const float* __restrict__ pe_w2, const float* __restrict__ pe_b2,
    const float* __restrict__ mlp_w1, const float* __restrict__ mlp_b1,
    const float* __restrict__ mlp_w2,
    const float* __restrict__ features, const float* __restrict__ points,
    _Float16* __restrict__ gB1, _Float16* __restrict__ gW2,
    float* __restrict__ b1c,
    _Float16* __restrict__ feat16, float4* __restrict__ pts4)
{
    const int bid = blockIdx.x, tid = threadIdx.x;
    if (bid >= 40) {
        if (bid == 2344) {
            if (tid < HID) {
                float a = mlp_b1[tid];
#pragma unroll 16
                for (int c = 0; c < 64; ++c)
                    a = fmaf(pe_b2[c], mlp_w1[(32 + c) * HID + tid], a);
                b1c[tid] = a;
            }
            return;
        }
        int t = (bid - 40) * 256 + tid;
        if (t < BB * NN * 8) {
            float4 v = ((const float4*)features)[t];
            f16x4 h;
            h[0] = (_Float16)v.x; h[1] = (_Float16)v.y;
            h[2] = (_Float16)v.z; h[3] = (_Float16)v.w;
            *(f16x4*)(feat16 + (size_t)t * 4) = h;
        } else {
            int i = t - BB * NN * 8;
            if (i < BB * NN) {
                const float* p = points + (size_t)i * 3;
                pts4[i] = make_float4(p[0], p[1], p[2], 0.f);
            }
        }
        return;
    }
    if (bid < 24) {   // gB1: tile (ks,nt); element e: l=e>>3, j=e&7
        int ks = bid >> 3, nt = bid & 7;
        for (int e = tid; e < 512; e += 256) {
            int l = e >> 3, j = e & 7;
            int k = ks * 32 + (l >> 4) * 8 + j;
            int n = nt * 16 + (l & 15);
            float v;
            if (k < 32) {
                v = mlp_w1[k * HID + n];
            } else {
                int r = k - 32;
                v = 0.f;
#pragma unroll 16
                for (int c = 0; c < 64; ++c)
                    v = fmaf(pe_w2[r * 64 + c], mlp_w1[(32 + c) * HID + n], v);
            }
            gB1[bid * 512 + e] = (_Float16)v;
        }
    } else {          // gW2 — pre-scaled by 1/32 so hm stores skip the mean mul
        int tb = bid - 24;
        int ks = tb >> 2, nt = tb & 3;
        for (int e = tid; e < 512; e += 256) {
            int l = e >> 3, j = e & 7;
            int k = ks * 32 + (l >> 4) * 8 + j;
            int n = nt * 16 + (l & 15);
            gW2[tb * 512 + e] = (_Float16)(mlp_w2[k * OUTF + n] * 0.03125f);
        }
    }
}

// ---------------------------------------------------------------------------
// Main: EXACT R6 champion structure (16-pt sHM, 44.5 KB LDS, (256,2),
// 3 blocks/CU — proven: 89.4 us, FETCH 9.4 MB, WRITE 16.4 MB, no spill).
// ONE change: array-free packed-f16 pe block (PE_FRAGS), no pointer arrays.
// ---------------------------------------------------------------------------
__global__ __launch_bounds__(256, 2) void DensityAwareFeatureAggregator_main(
    const float4* __restrict__ pts4,      // (B*N) padded, global index
    const _Float16* __restrict__ feat16,  // (B*N,32) f16
    const int*   __restrict__ nbr,        // (B,N,32)
    const float* __restrict__ pe_w1,      // (3,64)
    const float* __restrict__ pe_b1,      // (64)
    const float* __restrict__ b1c,        // (128) fused bias
    const _Float16* __restrict__ gB1,     // W1c frags (24 tiles)
    const _Float16* __restrict__ gW2,     // W2 frags (16 tiles, pre-scaled /32)
    const float* __restrict__ b2g,        // (64)
    float* __restrict__ out)              // (B,N,64)
{
    __shared__ __align__(16) _Float16 sB1[24 * 512];     // 24576 B
    __shared__ __align__(16) f16x8    sTabH[32];         //   512 B
    __shared__ __align__(16) ushort4  sRI[4][64];        //  2048 B
    __shared__ __align__(16) _Float16 sHM[4][16 * 136];  // 17408 B
    // total 44544 B -> 3 blocks/CU, 12 waves/CU

    const int t = threadIdx.x;
    {
        const uint4* g = (const uint4*)gB1;
        uint4* d = (uint4*)sB1;
        for (int i = t; i < 1536; i += 256) d[i] = g[i];
    }
    if (t < 32) {   // col-pair tables: {x0,x1,y0,y1,z0,z1,b0,b1}
        int cp = t;
        f16x8 e;
        e[0] = (_Float16)pe_w1[2 * cp];       e[1] = (_Float16)pe_w1[2 * cp + 1];
        e[2] = (_Float16)pe_w1[64 + 2 * cp];  e[3] = (_Float16)pe_w1[64 + 2 * cp + 1];
        e[4] = (_Float16)pe_w1[128 + 2 * cp]; e[5] = (_Float16)pe_w1[128 + 2 * cp + 1];
        e[6] = (_Float16)pe_b1[2 * cp];       e[7] = (_Float16)pe_b1[2 * cp + 1];
        sTabH[cp] = e;
    }
    __syncthreads();

    const int w = t >> 6, l = t & 63, q = l >> 4, c16 = l & 15;
    const int nb   = (blockIdx.x & 7) * 128 + (blockIdx.x >> 3);
    const int base = (nb * 4 + w) * 16;
    const int bo   = base & ~(NN - 1);   // batch offset into flat point ids

    f16x8 tab1[4], tab2[4];
#pragma unroll
    for (int u = 0; u < 4; ++u) {
        tab1[u] = sTabH[q * 4 + u];
        tab2[u] = sTabH[16 + q * 4 + u];
    }
    float bias1[8];
#pragma unroll
    for (int nt = 0; nt < 8; ++nt) bias1[nt] = b1c[nt * 16 + c16];

    const f16x8* B1f = (const f16x8*)sB1;
    _Float16* hmw = &sHM[w][0];

#pragma unroll 1
    for (int p2 = 0; p2 < 8; ++p2) {
        const int mA = base + 2 * p2;
        // ---- full-wave staging: lanes 0-31 point A, 32-63 point B ----
        int idx = nbr[(size_t)mA * KK + l];
        float4 pc = pts4[mA + (l >> 5)];
        float4 pn = pts4[bo + idx];
        ushort4 st;
        st.x = h2u((_Float16)(pn.x - pc.x));
        st.y = h2u((_Float16)(pn.y - pc.y));
        st.z = h2u((_Float16)(pn.z - pc.z));
        st.w = (unsigned short)idx;
        sRI[w][l] = st;
        ushort4 eA0 = sRI[w][c16];
        ushort4 eA1 = sRI[w][16 + c16];
        ushort4 eB0 = sRI[w][32 + c16];
        ushort4 eB1 = sRI[w][48 + c16];

        // ---- feature A-frags from fp16 global (MFMA A layout) ----
        f16x8 afA0 = ((const f16x8*)(feat16 + ((size_t)(bo + eA0.w)) * 32))[q];
        f16x8 afA1 = ((const f16x8*)(feat16 + ((size_t)(bo + eA1.w)) * 32))[q];
        f16x8 afB0 = ((const f16x8*)(feat16 + ((size_t)(bo + eB0.w)) * 32))[q];
        f16x8 afB1 = ((const f16x8*)(feat16 + ((size_t)(bo + eB1.w)) * 32))[q];

        // ---- pe A-frags: array-free, packed f16x2 math ----
        f16x8 apA10, apA20, apA11, apA21, apB10, apB20, apB11, apB21;
        PE_FRAGS(eA0, apA10, apA20);
        PE_FRAGS(eA1, apA11, apA21);
        PE_FRAGS(eB0, apB10, apB20);
        PE_FRAGS(eB1, apB11, apB21);

        // ---- per-N-tile: 3 shared B-frags, 12 MFMAs, reduce ----
#pragma unroll 2
        for (int nt = 0; nt < 8; ++nt) {
            f16x8 bf0 = B1f[nt * 64 + l];
            f16x8 bf1 = B1f[(8 + nt) * 64 + l];
            f16x8 bf2 = B1f[(16 + nt) * 64 + l];
            f32x4 aA0, aA1, aB0, aB1;
            aA0[0] = aA0[1] = aA0[2] = aA0[3] = bias1[nt];
            aA1 = aA0; aB0 = aA0; aB1 = aA0;
            aA0 = __builtin_amdgcn_mfma_f32_16x16x32_f16(afA0,  bf0, aA0, 0, 0, 0);
            aA1 = __builtin_amdgcn_mfma_f32_16x16x32_f16(afA1,  bf0, aA1, 0, 0, 0);
            aB0 = __builtin_amdgcn_mfma_f32_16x16x32_f16(afB0,  bf0, aB0, 0, 0, 0);
            aB1 = __builtin_amdgcn_mfma_f32_16x16x32_f16(afB1,  bf0, aB1, 0, 0, 0);
            aA0 = __builtin_amdgcn_mfma_f32_16x16x32_f16(apA10, bf1, aA0, 0, 0, 0);
            aA1 = __builtin_amdgcn_mfma_f32_16x16x32_f16(apA11, bf1, aA1, 0, 0, 0);
            aB0 = __builtin_amdgcn_mfma_f32_16x16x32_f16(apB10, bf1, aB0, 0, 0, 0);
            aB1 = __builtin_amdgcn_mfma_f32_16x16x32_f16(apB11, bf1, aB1, 0, 0, 0);
            aA0 = __builtin_amdgcn_mfma_f32_16x16x32_f16(apA20, bf2, aA0, 0, 0, 0);
            aA1 = __builtin_amdgcn_mfma_f32_16x16x32_f16(apA21, bf2, aA1, 0, 0, 0);
            aB0 = __builtin_amdgcn_mfma_f32_16x16x32_f16(apB20, bf2, aB0, 0, 0, 0);
            aB1 = __builtin_amdgcn_mfma_f32_16x16x32_f16(apB21, bf2, aB1, 0, 0, 0);

            float sA = fmaxf(aA0[0], 0.f) + fmaxf(aA0[1], 0.f)
                     + fmaxf(aA0[2], 0.f) + fmaxf(aA0[3], 0.f)
                     + fmaxf(aA1[0], 0.f) + fmaxf(aA1[1], 0.f)
                     + fmaxf(aA1[2], 0.f) + fmaxf(aA1[3], 0.f);
            float sB = fmaxf(aB0[0], 0.f) + fmaxf(aB0[1], 0.f)
                     + fmaxf(aB0[2], 0.f) + fmaxf(aB0[3], 0.f)
                     + fmaxf(aB1[0], 0.f) + fmaxf(aB1[1], 0.f)
                     + fmaxf(aB1[2], 0.f) + fmaxf(aB1[3], 0.f);
            sA += __shfl_xor(sA, 16, 64);
            sA += __shfl_xor(sA, 32, 64);
            sB += __shfl_xor(sB, 16, 64);
            sB += __shfl_xor(sB, 32, 64);
            if (q == 0) {
                hmw[(2 * p2) * 136 + nt * 16 + c16]     = (_Float16)sA;
                hmw[(2 * p2 + 1) * 136 + nt * 16 + c16] = (_Float16)sB;
            }
        }
    }

    // ---- epilogue: OUT(16x64) = HM(16x128) @ W2s + b2 (verified R2-R7) ----
    const f16x8* W2f = (const f16x8*)gW2;
    f32x4 acc2[4];
#pragma unroll
    for (int nt = 0; nt < 4; ++nt) {
        f32x4 z; float bv = b2g[nt * 16 + c16];
        z[0] = z[1] = z[2] = z[3] = bv;
        acc2[nt] = z;
    }
#pragma unroll
    for (int ks = 0; ks < 4; ++ks) {
        f16x8 a2 = *(const f16x8*)&hmw[c16 * 136 + ks * 32 + q * 8];
#pragma unroll
        for (int nt = 0; nt < 4; ++nt) {
            f16x8 bf = W2f[(ks * 4 + nt) * 64 + l];
            acc2[nt] = __builtin_amdgcn_mfma_f32_16x16x32_f16(a2, bf, acc2[nt], 0, 0, 0);
        }
    }
#pragma unroll
    for (int nt = 0; nt < 4; ++nt)
#pragma unroll
        for (int r = 0; r < 4; ++r)
            out[(size_t)(base + q * 4 + r) * OUTF + nt * 16 + c16] = acc2[nt][r];
}

// ---------------------------------------------------------------------------
extern "C" void kernel_launch(void* const* d_in, const int* in_sizes, int n_in,
                              void* d_out, int out_size, void* d_ws, size_t ws_size,
                              hipStream_t stream)
{
    const float* points   = (const float*)d_in[0];
    const float* features = (const float*)d_in[1];
    // d_in[2] density: provably unused (softmax over K identical values = 1/K)
    const int*   nbr      = (const int*)d_in[3];
    const float* pe_w1    = (const float*)d_in[4];
    const float* pe_b1    = (const float*)d_in[5];
    const float* pe_w2    = (const float*)d_in[6];
    const float* pe_b2    = (const float*)d_in[7];
    const float* mlp_w1   = (const float*)d_in[8];
    const float* mlp_b1   = (const float*)d_in[9];
    const float* mlp_w2   = (const float*)d_in[10];
    const float* mlp_b2   = (const float*)d_in[11];

    float* wsf = (float*)d_ws;
    float*    b1c    = wsf;                         // 128 f32
    _Float16* gB1    = (_Float16*)(wsf + 128);      // 12288 f16
    _Float16* gW2    = (_Float16*)(wsf + 6272);     // 8192 f16
    float4*   pts4   = (float4*)(wsf + 10368);      // 65536 float4
    _Float16* feat16 = (_Float16*)(wsf + 272512);   // 2097152 f16

    prep_all<<<2345, 256, 0, stream>>>(
        pe_w2, pe_b2, mlp_w1, mlp_b1, mlp_w2, features, points,
        gB1, gW2, b1c, feat16, pts4);

    DensityAwareFeatureAggregator_main<<<1024, 256, 0, stream>>>(
        pts4, feat16, nbr, pe_w1, pe_b1, b1c, gB1, gW2, mlp_b2,
        (float*)d_out);
}